// Round 14
// baseline (261.758 us; speedup 1.0000x reference)
//
#include <hip/hip_runtime.h>
#include <hip/hip_bf16.h>

#define BROWS 32768
#define CDIM 1000
#define CPAD 1024
#define HDIM 128
// Bijective LDS word swizzle for the sort region (proven v6).
#define SWZ(w) ((w) ^ ((((w) >> 5) & 7) << 2))

typedef __attribute__((ext_vector_type(8))) short short8;
typedef __attribute__((ext_vector_type(4))) float f32x4;

__device__ inline unsigned short f2bf(float x) {
    unsigned int b = __float_as_uint(x);
    unsigned int r = (b + 0x7FFFu + ((b >> 16) & 1u)) >> 16;  // RNE
    return (unsigned short)r;
}
__device__ inline float bf2f(unsigned short u) {
    return __uint_as_float(((unsigned int)u) << 16);
}

// ---------------- prep: transpose weights to [N][K] bf16, zero-padded ----------------
__global__ __launch_bounds__(256) void k_prep(const float* __restrict__ W1,
                                              const float* __restrict__ W2,
                                              const float* __restrict__ W3,
                                              unsigned short* __restrict__ W1t,
                                              unsigned short* __restrict__ W2t,
                                              unsigned short* __restrict__ W3t) {
    const int idx = blockIdx.x * 256 + threadIdx.x;  // [0, 131072)
    {   // W1t[n][k], n<128, k<1024 ; W1 is [1000][128]
        const int n = idx >> 10, k = idx & 1023;
        W1t[idx] = (k < CDIM) ? f2bf(W1[(size_t)k * HDIM + n]) : (unsigned short)0;
    }
    {   // W3t[n][k], n<1024, k<128 ; W3 is [128][1000]
        const int n = idx >> 7, k = idx & 127;
        W3t[idx] = (n < CDIM) ? f2bf(W3[(size_t)k * CDIM + n]) : (unsigned short)0;
    }
    if (idx < 16384) {  // W2t[n][k], 128x128 ; W2 is [128][128]
        const int n = idx >> 7, k = idx & 127;
        W2t[idx] = f2bf(W2[(size_t)k * HDIM + n]);
    }
}

// ---------------- fused MLP: softmax -> gemm1 -> gemm2 -> gemm3 -> cal (global) ------
// = r13 k_fused phases 1-4 (verified correct). One block = 16 rows, 256 threads.
// LDS 40KB (-> 4 blocks/CU): pbuf 32KB (p bf16), hbuf 8KB (h1 uint4[0,256),
// h2 uint4[256,512)). cal written straight from accumulators to global (compact
// ldo=CDIM) - no LDS round trip. Kills r9's prob(64w+67r) + h1/h2(32) MB traffic.
__global__ __launch_bounds__(256) void k_mlp(const float* __restrict__ logits,
                                             const unsigned short* __restrict__ W1t,
                                             const float* __restrict__ b1,
                                             const unsigned short* __restrict__ W2t,
                                             const float* __restrict__ b2,
                                             const unsigned short* __restrict__ W3t,
                                             const float* __restrict__ b3,
                                             unsigned short* __restrict__ cal) {
    __shared__ uint4 pbuf[16 * 128];
    __shared__ unsigned int hbuf[2048];

    const int tid = threadIdx.x, lane = tid & 63, wv = tid >> 6;
    const int l15 = lane & 15, l4 = lane >> 4;
    const int row0 = blockIdx.x << 4;
    const int base = lane << 4;

    // ---------- phase 1: softmax, wave wv owns rows 4wv..4wv+3 ----------
#pragma unroll
    for (int rr = 0; rr < 4; ++rr) {
        const int r = (wv << 2) + rr;
        const float* lrow = logits + (size_t)(row0 + r) * CDIM;
        float lg[16];
#pragma unroll
        for (int q = 0; q < 4; ++q) {
            const int c = base + (q << 2);
            if (c < CDIM) {
                const float4 v4 = *reinterpret_cast<const float4*>(lrow + c);
                lg[q * 4] = v4.x; lg[q * 4 + 1] = v4.y; lg[q * 4 + 2] = v4.z; lg[q * 4 + 3] = v4.w;
            } else {
                lg[q * 4] = lg[q * 4 + 1] = lg[q * 4 + 2] = lg[q * 4 + 3] = -INFINITY;
            }
        }
        float mx = lg[0];
#pragma unroll
        for (int e = 1; e < 16; ++e) mx = fmaxf(mx, lg[e]);
#pragma unroll
        for (int off = 32; off >= 1; off >>= 1) mx = fmaxf(mx, __shfl_xor(mx, off));
        float p[16], s = 0.f;
#pragma unroll
        for (int e = 0; e < 16; ++e) { p[e] = __expf(lg[e] - mx); s += p[e]; }
#pragma unroll
        for (int off = 32; off >= 1; off >>= 1) s += __shfl_xor(s, off);
        const float inv = 1.f / s;
        unsigned int w[8];
#pragma unroll
        for (int i = 0; i < 8; ++i) {
            const unsigned int lo = f2bf(p[2 * i] * inv);
            const unsigned int hi = f2bf(p[2 * i + 1] * inv);
            w[i] = lo | (hi << 16);
        }
        uint4 o0, o1;
        o0.x = w[0]; o0.y = w[1]; o0.z = w[2]; o0.w = w[3];
        o1.x = w[4]; o1.y = w[5]; o1.z = w[6]; o1.w = w[7];
        pbuf[r * 128 + ((2 * lane) ^ (r & 7))] = o0;
        pbuf[r * 128 + ((2 * lane + 1) ^ (r & 7))] = o1;
    }
    __syncthreads();

    // ---------- phase 2: gemm1  h1 = relu(p @ W1 + b1), M=16 N=128 K=1024 ----------
    {
        const int wn = wv << 5;   // 32 cols per wave
        f32x4 acc[2] = {};
#pragma unroll 8
        for (int kk = 0; kk < 32; ++kk) {
            const short8 a = *reinterpret_cast<const short8*>(
                &pbuf[l15 * 128 + (((kk << 2) + l4) ^ (l15 & 7))]);
#pragma unroll
            for (int nf = 0; nf < 2; ++nf) {
                const int n = wn + (nf << 4) + l15;
                const short8 b = *reinterpret_cast<const short8*>(
                    W1t + (size_t)n * CPAD + (kk << 5) + (l4 << 3));
                acc[nf] = __builtin_amdgcn_mfma_f32_16x16x32_bf16(a, b, acc[nf], 0, 0, 0);
            }
        }
        unsigned short* h1 = (unsigned short*)hbuf;   // shorts [0, 2048)
#pragma unroll
        for (int nf = 0; nf < 2; ++nf) {
            const int n = wn + (nf << 4) + l15;
            const float bv = b1[n];
#pragma unroll
            for (int j = 0; j < 4; ++j) {
                const int m = (l4 << 2) + j;
                h1[m * 128 + ((((n >> 3) ^ (m & 7))) << 3) + (n & 7)] =
                    f2bf(fmaxf(acc[nf][j] + bv, 0.f));
            }
        }
    }
    __syncthreads();

    // ---------- phase 3: gemm2  h2 = relu(h1 @ W2 + b2), M=16 N=128 K=128 ----------
    {
        const int wn = wv << 5;
        f32x4 acc[2] = {};
#pragma unroll
        for (int kk = 0; kk < 4; ++kk) {
            const short8 a = *reinterpret_cast<const short8*>(
                &((const uint4*)hbuf)[l15 * 16 + (((kk << 2) + l4) ^ (l15 & 7))]);
#pragma unroll
            for (int nf = 0; nf < 2; ++nf) {
                const int n = wn + (nf << 4) + l15;
                const short8 b = *reinterpret_cast<const short8*>(
                    W2t + (size_t)n * HDIM + (kk << 5) + (l4 << 3));
                acc[nf] = __builtin_amdgcn_mfma_f32_16x16x32_bf16(a, b, acc[nf], 0, 0, 0);
            }
        }
        unsigned short* h2 = (unsigned short*)hbuf + 2048;   // shorts [2048,4096) = uint4 [256,512)
#pragma unroll
        for (int nf = 0; nf < 2; ++nf) {
            const int n = wn + (nf << 4) + l15;
            const float bv = b2[n];
#pragma unroll
            for (int j = 0; j < 4; ++j) {
                const int m = (l4 << 2) + j;
                h2[m * 128 + ((((n >> 3) ^ (m & 7))) << 3) + (n & 7)] =
                    f2bf(fmaxf(acc[nf][j] + bv, 0.f));
            }
        }
    }
    __syncthreads();

    // ---------- phase 4: gemm3  cal = epi(h2 @ W3 + b3) -> GLOBAL, M=16 N=1024 K=128 --
    {
        f32x4 acc3[16] = {};
#pragma unroll
        for (int kk = 0; kk < 4; ++kk) {
            const short8 a = *reinterpret_cast<const short8*>(
                &((const uint4*)hbuf)[256 + l15 * 16 + (((kk << 2) + l4) ^ (l15 & 7))]);
#pragma unroll
            for (int nf = 0; nf < 16; ++nf) {
                const int n = (wv << 8) + (nf << 4) + l15;
                const short8 b = *reinterpret_cast<const short8*>(
                    W3t + (size_t)n * HDIM + (kk << 5) + (l4 << 3));
                acc3[nf] = __builtin_amdgcn_mfma_f32_16x16x32_bf16(a, b, acc3[nf], 0, 0, 0);
            }
        }
#pragma unroll
        for (int nf = 0; nf < 16; ++nf) {
            const int n = (wv << 8) + (nf << 4) + l15;
            if (n >= CDIM) continue;          // compact cal: skip pad cols
            const float bv = b3[n];
#pragma unroll
            for (int j = 0; j < 4; ++j) {
                const int m = (l4 << 2) + j;
                float v = acc3[nf][j] + bv;
                if (n != CDIM - 1) v = 1.f / (1.f + __expf(-v));
                cal[(size_t)(row0 + m) * CDIM + n] = f2bf(v);
            }
        }
    }
}

// ---------------- sort + finish: r9-proven counting sort v6, one wave per row ---------
__global__ __launch_bounds__(256) void k_sortfinish(const float* __restrict__ logits,
                                                    const unsigned short* __restrict__ cal,
                                                    float* __restrict__ out) {
    __shared__ unsigned int shm[4 * 1024];
    const int wv = threadIdx.x >> 6, lane = threadIdx.x & 63;
    const int row = (blockIdx.x << 2) + wv;
    unsigned int* sm = &shm[wv << 10];
    const int base = lane << 4;

    int cb[4];
#pragma unroll
    for (int j = 0; j < 4; ++j) { const int wd = base + (j << 2); cb[j] = SWZ(wd); }

    // zero histogram (4 x b128 across the wave)
    {
        uint4 z; z.x = 0; z.y = 0; z.z = 0; z.w = 0;
#pragma unroll
        for (int j = 0; j < 4; ++j) *reinterpret_cast<uint4*>(&sm[cb[j]]) = z;
    }

    // ---- load logits + hoist cal row (compact ldo = CDIM; rows 16B-aligned) ----
    const float* lrow = logits + (size_t)row * CDIM;
    float lg[16];
#pragma unroll
    for (int q = 0; q < 4; ++q) {
        const int c = base + (q << 2);
        if (c < CDIM) {
            const float4 v4 = *reinterpret_cast<const float4*>(lrow + c);
            lg[q * 4] = v4.x; lg[q * 4 + 1] = v4.y; lg[q * 4 + 2] = v4.z; lg[q * 4 + 3] = v4.w;
        } else {
            lg[q * 4] = lg[q * 4 + 1] = lg[q * 4 + 2] = lg[q * 4 + 3] = -INFINITY;
        }
    }
    const unsigned short* crow = cal + (size_t)row * CDIM + base;
    const uint4 c0v = *reinterpret_cast<const uint4*>(crow);      // cols >= 1000 overread
    const uint4 c1v = *reinterpret_cast<const uint4*>(crow + 8);  // into ws: safe, unused

    // ---- softmax (fp32, inline) ----
    float mx = lg[0];
#pragma unroll
    for (int e = 1; e < 16; ++e) mx = fmaxf(mx, lg[e]);
#pragma unroll
    for (int off = 32; off >= 1; off >>= 1) mx = fmaxf(mx, __shfl_xor(mx, off));
    float p[16], s = 0.f;
#pragma unroll
    for (int e = 0; e < 16; ++e) { p[e] = __expf(lg[e] - mx); s += p[e]; }
#pragma unroll
    for (int off = 32; off >= 1; off >>= 1) s += __shfl_xor(s, off);
    const float inv = 1.f / s;
#pragma unroll
    for (int e = 0; e < 16; ++e) p[e] *= inv;

    // ---- single atomic pass: histogram count + stable in-bucket offset ----
    unsigned int offv[16]; int swk[16];
#pragma unroll
    for (int e = 0; e < 16; ++e) {
        const unsigned int key = __float_as_uint(p[e]) >> 20;  // 11-bit monotone, <= 1016
        swk[e] = SWZ((int)key);
        offv[e] = (base + e < CDIM) ? atomicAdd(&sm[swk[e]], 1u) : 0u;
    }

    // ---- bucket suffix-scan: start[b] = sum_{b' > b} cnt[b'] (4 x b128 r/w) ----
    {
        unsigned int c16[16];
#pragma unroll
        for (int j = 0; j < 4; ++j) {
            const uint4 v4 = *reinterpret_cast<const uint4*>(&sm[cb[j]]);
            c16[4 * j] = v4.x; c16[4 * j + 1] = v4.y; c16[4 * j + 2] = v4.z; c16[4 * j + 3] = v4.w;
        }
        unsigned int lsum = 0;
#pragma unroll
        for (int e = 0; e < 16; ++e) lsum += c16[e];
        unsigned int suf = lsum;
#pragma unroll
        for (int off = 1; off < 64; off <<= 1) {
            const unsigned int u = __shfl_down(suf, off);
            if (lane + off < 64) suf += u;
        }
        unsigned int run = suf - lsum;  // sum over lanes > this lane
        unsigned int stv[16];
#pragma unroll
        for (int e = 15; e >= 0; --e) { stv[e] = run; run += c16[e]; }
#pragma unroll
        for (int j = 0; j < 4; ++j) {
            uint4 v4;
            v4.x = stv[4 * j]; v4.y = stv[4 * j + 1]; v4.z = stv[4 * j + 2]; v4.w = stv[4 * j + 3];
            *reinterpret_cast<uint4*>(&sm[cb[j]]) = v4;
        }
    }

    // ---- rank = start[key] + offset; swizzled rank addr reused twice ----
    int swr[16];
#pragma unroll
    for (int e = 0; e < 16; ++e) {
        const int rk = (base + e < CDIM) ? (int)(sm[swk[e]] + offv[e]) : 1023;
        swr[e] = SWZ(rk);
    }

    // ---- scatter full-precision probs to rank order ----
#pragma unroll
    for (int e = 0; e < 16; ++e)
        if (base + e < CDIM) sm[swr[e]] = __float_as_uint(p[e]);

    // ---- sorted-prob blocked read (4 x b128) ----
    float sp[16];
#pragma unroll
    for (int j = 0; j < 4; ++j) {
        const uint4 v4 = *reinterpret_cast<const uint4*>(&sm[cb[j]]);
        sp[4 * j] = __uint_as_float(v4.x); sp[4 * j + 1] = __uint_as_float(v4.y);
        sp[4 * j + 2] = __uint_as_float(v4.z); sp[4 * j + 3] = __uint_as_float(v4.w);
    }
    const float spn_next = __shfl_down(sp[0], 1);
    const unsigned int cw[8] = {c0v.x, c0v.y, c0v.z, c0v.w, c1v.x, c1v.y, c1v.z, c1v.w};
    float v[16];
#pragma unroll
    for (int e = 0; e < 16; ++e) {
        const int r = base + e;
        const float cv = bf2f((unsigned short)((cw[e >> 1] >> ((e & 1) * 16)) & 0xFFFFu));
        const float spn = (e < 15) ? sp[e + 1] : spn_next;
        float val;
        if (r < CDIM - 1) val = (sp[e] - spn) * cv;
        else if (r == CDIM - 1) val = cv;
        else val = 0.f;
        v[e] = val;
    }
    // suffix sum over rank space
    float lsuf[16], run = 0.f;
#pragma unroll
    for (int e = 15; e >= 0; --e) { run += v[e]; lsuf[e] = run; }
    float pi = run;
#pragma unroll
    for (int off = 1; off < 64; off <<= 1) {
        const float u = __shfl_up(pi, off);
        if (lane >= off) pi += u;
    }
    const float tot = __shfl(pi, 63);
    const float after = tot - pi;

    // ---- Sarr overwrites sorted probs (4 x b128), then gather by rank ----
#pragma unroll
    for (int j = 0; j < 4; ++j) {
        uint4 v4;
        v4.x = __float_as_uint(lsuf[4 * j] + after);
        v4.y = __float_as_uint(lsuf[4 * j + 1] + after);
        v4.z = __float_as_uint(lsuf[4 * j + 2] + after);
        v4.w = __float_as_uint(lsuf[4 * j + 3] + after);
        *reinterpret_cast<uint4*>(&sm[cb[j]]) = v4;
    }
    float f[16];
#pragma unroll
    for (int e = 0; e < 16; ++e) f[e] = __uint_as_float(sm[swr[e]]);
#pragma unroll
    for (int q = 0; q < 4; ++q) {
        const int c = base + (q << 2);
        if (c < CDIM) {
            float4 o;
            o.x = lg[q * 4] + f[q * 4];
            o.y = lg[q * 4 + 1] + f[q * 4 + 1];
            o.z = lg[q * 4 + 2] + f[q * 4 + 2];
            o.w = lg[q * 4 + 3] + f[q * 4 + 3];
            *reinterpret_cast<float4*>(out + (size_t)row * CDIM + c) = o;
        }
    }
}

// ---------------- host ----------------
extern "C" void kernel_launch(void* const* d_in, const int* in_sizes, int n_in,
                              void* d_out, int out_size, void* d_ws, size_t ws_size,
                              hipStream_t stream) {
    const float* logits = (const float*)d_in[0];
    const float* W1 = (const float*)d_in[1];
    const float* b1 = (const float*)d_in[2];
    const float* W2 = (const float*)d_in[3];
    const float* b2 = (const float*)d_in[4];
    const float* W3 = (const float*)d_in[5];
    const float* b3 = (const float*)d_in[6];
    float* out = (float*)d_out;

    char* ws = (char*)d_ws;
    unsigned short* cal = (unsigned short*)ws;                 // 32768*1000*2 = 62.5 MB
    unsigned short* W1t = (unsigned short*)(ws + 65536000);    // 256 KB (16B-aligned)
    unsigned short* W2t = (unsigned short*)(ws + 65798144);    // 32 KB
    unsigned short* W3t = (unsigned short*)(ws + 65830912);    // 256 KB -> 66.1 MB total

    k_prep<<<512, 256, 0, stream>>>(W1, W2, W3, W1t, W2t, W3t);
    k_mlp<<<BROWS / 16, 256, 0, stream>>>(logits, W1t, b1, W2t, b2, W3t, b3, cal);
    k_sortfinish<<<BROWS / 4, 256, 0, stream>>>(logits, cal, out);
}

// Round 15
// 178.138 us; speedup vs baseline: 1.4694x; 1.4694x over previous
//
#include <hip/hip_runtime.h>
#include <hip/hip_bf16.h>

#define BROWS 32768
#define CDIM 1000
#define CPAD 1024
#define HDIM 128
// Bijective LDS word swizzle (proven v6): XOR bits5-7 into bits2-4; keeps 4-word
// chunks contiguous (b128) and balances the 64B-lane-stride pattern across banks.
#define SWZ(w) ((w) ^ ((((w) >> 5) & 7) << 2))

typedef __attribute__((ext_vector_type(8))) short short8;
typedef __attribute__((ext_vector_type(4))) float f32x4;

__device__ inline unsigned short f2bf(float x) {
    unsigned int b = __float_as_uint(x);
    unsigned int r = (b + 0x7FFFu + ((b >> 16) & 1u)) >> 16;  // RNE
    return (unsigned short)r;
}
__device__ inline float bf2f(unsigned short u) {
    return __uint_as_float(((unsigned int)u) << 16);
}

// ---------------- prep: transpose weights to [N][K] bf16, zero-padded ----------------
__global__ __launch_bounds__(256) void k_prep(const float* __restrict__ W1,
                                              const float* __restrict__ W2,
                                              const float* __restrict__ W3,
                                              unsigned short* __restrict__ W1t,
                                              unsigned short* __restrict__ W2t,
                                              unsigned short* __restrict__ W3t) {
    const int idx = blockIdx.x * 256 + threadIdx.x;  // [0, 131072)
    {   // W1t[n][k], n<128, k<1024 ; W1 is [1000][128]
        const int n = idx >> 10, k = idx & 1023;
        W1t[idx] = (k < CDIM) ? f2bf(W1[(size_t)k * HDIM + n]) : (unsigned short)0;
    }
    {   // W3t[n][k], n<1024, k<128 ; W3 is [128][1000]
        const int n = idx >> 7, k = idx & 127;
        W3t[idx] = (n < CDIM) ? f2bf(W3[(size_t)k * CDIM + n]) : (unsigned short)0;
    }
    if (idx < 16384) {  // W2t[n][k], 128x128 ; W2 is [128][128]
        const int n = idx >> 7, k = idx & 127;
        W2t[idx] = f2bf(W2[(size_t)k * HDIM + n]);
    }
}

// ---------------- softmax: one wave per row, bf16 prob (padded 1024) + rstat ---------
__global__ __launch_bounds__(256) void k_softmax(const float* __restrict__ logits,
                                                 unsigned short* __restrict__ prob,
                                                 float2* __restrict__ rstat) {
    const int wv = threadIdx.x >> 6, lane = threadIdx.x & 63;
    const int row = (blockIdx.x << 2) + wv;
    const int base = lane << 4;
    const float* lrow = logits + (size_t)row * CDIM;
    float lg[16];
#pragma unroll
    for (int q = 0; q < 4; ++q) {
        const int c = base + (q << 2);
        if (c < CDIM) {
            const float4 v4 = *reinterpret_cast<const float4*>(lrow + c);
            lg[q * 4] = v4.x; lg[q * 4 + 1] = v4.y; lg[q * 4 + 2] = v4.z; lg[q * 4 + 3] = v4.w;
        } else {
            lg[q * 4] = lg[q * 4 + 1] = lg[q * 4 + 2] = lg[q * 4 + 3] = -INFINITY;
        }
    }
    float mx = lg[0];
#pragma unroll
    for (int e = 1; e < 16; ++e) mx = fmaxf(mx, lg[e]);
#pragma unroll
    for (int off = 32; off >= 1; off >>= 1) mx = fmaxf(mx, __shfl_xor(mx, off));
    float p[16], s = 0.f;
#pragma unroll
    for (int e = 0; e < 16; ++e) { p[e] = __expf(lg[e] - mx); s += p[e]; }
#pragma unroll
    for (int off = 32; off >= 1; off >>= 1) s += __shfl_xor(s, off);
    const float inv = 1.f / s;
    unsigned int w[8];
#pragma unroll
    for (int i = 0; i < 8; ++i) {
        const unsigned int lo = f2bf(p[2 * i] * inv);
        const unsigned int hi = f2bf(p[2 * i + 1] * inv);
        w[i] = lo | (hi << 16);
    }
    uint4 o0, o1;
    o0.x = w[0]; o0.y = w[1]; o0.z = w[2]; o0.w = w[3];
    o1.x = w[4]; o1.y = w[5]; o1.z = w[6]; o1.w = w[7];
    uint4* dst = reinterpret_cast<uint4*>(prob + (size_t)row * CPAD + base);
    dst[0] = o0; dst[1] = o1;
    if (lane == 0) rstat[row] = make_float2(mx, inv);   // bitwise-same stats for sortfinish
}

// ---------------- GEMM: C[M,N] = epi(A[M,K] @ Bt[N,K]^T + bias) ----------------------
// 512 threads = 8 waves (4m x 2n), block tile 128x128, BK=64, XOR-swizzled LDS chunks.
// EPI 0: relu(v + bias), all cols. EPI 1: sigmoid(v+bias) except col nlimit-1 raw;
//        stores only n < nlimit (compact ldo).
// NOTE: safe to call with outp aliasing A (in-place per-128-row-block): the barrier
// before the last MFMA phase orders all global A reads before epilogue writes, and
// blocks touch disjoint row ranges.
template <int EPI>
__global__ __launch_bounds__(512) void k_gemm(const unsigned short* __restrict__ A, int lda,
                                              const unsigned short* __restrict__ Bt, int ldb,
                                              const float* __restrict__ bias,
                                              unsigned short* __restrict__ outp, int ldo,
                                              int K, int nlimit) {
    __shared__ uint4 As[128 * 8];
    __shared__ uint4 Bs[128 * 8];
    const int tid = threadIdx.x;
    const int bm = blockIdx.x, bn = blockIdx.y;
    const int lane = tid & 63, w = tid >> 6;
    const int wm = (w >> 1) << 5;
    const int wn = (w & 1) << 6;
    const int l15 = lane & 15, l4 = lane >> 4;
    f32x4 acc[2][4] = {};

    for (int k0 = 0; k0 < K; k0 += 64) {
        __syncthreads();
#pragma unroll
        for (int i = 0; i < 2; ++i) {
            const int cid = tid + (i << 9);
            const int r = cid >> 3, c = cid & 7;
            As[(r << 3) + (c ^ (r & 7))] =
                *reinterpret_cast<const uint4*>(A + (size_t)(bm * 128 + r) * lda + k0 + (c << 3));
            Bs[(r << 3) + (c ^ (r & 7))] =
                *reinterpret_cast<const uint4*>(Bt + (size_t)(bn * 128 + r) * ldb + k0 + (c << 3));
        }
        __syncthreads();
#pragma unroll
        for (int kk = 0; kk < 2; ++kk) {
            short8 a[2], b[4];
#pragma unroll
            for (int mf = 0; mf < 2; ++mf) {
                const int r = wm + (mf << 4) + l15;
                a[mf] = *reinterpret_cast<const short8*>(&As[(r << 3) + (((kk << 2) + l4) ^ (r & 7))]);
            }
#pragma unroll
            for (int nf = 0; nf < 4; ++nf) {
                const int r = wn + (nf << 4) + l15;
                b[nf] = *reinterpret_cast<const short8*>(&Bs[(r << 3) + (((kk << 2) + l4) ^ (r & 7))]);
            }
#pragma unroll
            for (int mf = 0; mf < 2; ++mf)
#pragma unroll
                for (int nf = 0; nf < 4; ++nf)
                    acc[mf][nf] = __builtin_amdgcn_mfma_f32_16x16x32_bf16(a[mf], b[nf], acc[mf][nf], 0, 0, 0);
        }
    }
#pragma unroll
    for (int mf = 0; mf < 2; ++mf) {
#pragma unroll
        for (int nf = 0; nf < 4; ++nf) {
            const int n = (bn << 7) + wn + (nf << 4) + l15;
            if (EPI == 1 && n >= nlimit) continue;   // compact output: skip pad cols
            const float bv = bias[n];
#pragma unroll
            for (int r = 0; r < 4; ++r) {
                const int m = (bm << 7) + wm + (mf << 4) + (l4 << 2) + r;
                float v = acc[mf][nf][r] + bv;
                if (EPI == 0) {
                    v = fmaxf(v, 0.f);
                } else {
                    if (n != nlimit - 1) v = 1.f / (1.f + __expf(-v));
                }
                outp[(size_t)m * ldo + n] = f2bf(v);
            }
        }
    }
}

// ---------------- sort + finish v7: counting sort, 4 rows/wave, prefetch -------------
// Per row: identical v6 pipeline (11-bit key, single atomic pass, suffix-scan,
// rank = start[key]+offset, scatter/blocked-read/suffix-sum/gather, SWZ LDS).
// New: (a) mx/inv from precomputed rstat (drops both 6-shfl reduce chains);
// (b) each wave processes 4 rows with double-buffered prefetch of the next row's
// logits/cal/rstat, hiding HBM/L3 latency under the current row's compute.
__global__ __launch_bounds__(256) void k_sortfinish(const float* __restrict__ logits,
                                                    const float2* __restrict__ rstat,
                                                    const unsigned short* __restrict__ cal,
                                                    float* __restrict__ out) {
    __shared__ unsigned int shm[4 * 1024];
    const int wv = threadIdx.x >> 6, lane = threadIdx.x & 63;
    unsigned int* sm = &shm[wv << 10];
    const int base = lane << 4;
    const int row0 = (blockIdx.x << 4) + (wv << 2);   // wave owns rows row0..row0+3

    int cb[4];
#pragma unroll
    for (int j = 0; j < 4; ++j) { const int wd = base + (j << 2); cb[j] = SWZ(wd); }

    // double-buffered row inputs (all indices compile-time after unroll)
    float4 lgb[2][4]; uint4 c0b[2], c1b[2]; float2 stb[2];
    {
        const float* lrow = logits + (size_t)row0 * CDIM;
#pragma unroll
        for (int q = 0; q < 4; ++q) {
            const int c = base + (q << 2);
            lgb[0][q] = (c < CDIM) ? *reinterpret_cast<const float4*>(lrow + c)
                                   : make_float4(-INFINITY, -INFINITY, -INFINITY, -INFINITY);
        }
        const unsigned short* crow = cal + (size_t)row0 * CDIM + base;
        c0b[0] = *reinterpret_cast<const uint4*>(crow);       // cols>=1000 overread: in-ws, unused
        c1b[0] = *reinterpret_cast<const uint4*>(crow + 8);
        stb[0] = rstat[row0];
    }

#pragma unroll
    for (int rr = 0; rr < 4; ++rr) {
        const int buf = rr & 1;
        const int grow = row0 + rr;

        // ---- prefetch next row (issued before this row's compute) ----
        if (rr < 3) {
            const int nrow = grow + 1;
            const float* lrow = logits + (size_t)nrow * CDIM;
#pragma unroll
            for (int q = 0; q < 4; ++q) {
                const int c = base + (q << 2);
                lgb[buf ^ 1][q] = (c < CDIM) ? *reinterpret_cast<const float4*>(lrow + c)
                                             : make_float4(-INFINITY, -INFINITY, -INFINITY, -INFINITY);
            }
            const unsigned short* crow = cal + (size_t)nrow * CDIM + base;
            c0b[buf ^ 1] = *reinterpret_cast<const uint4*>(crow);
            c1b[buf ^ 1] = *reinterpret_cast<const uint4*>(crow + 8);
            stb[buf ^ 1] = rstat[nrow];
        }

        // ---- unpack current row ----
        float lg[16];
#pragma unroll
        for (int q = 0; q < 4; ++q) {
            lg[q * 4] = lgb[buf][q].x; lg[q * 4 + 1] = lgb[buf][q].y;
            lg[q * 4 + 2] = lgb[buf][q].z; lg[q * 4 + 3] = lgb[buf][q].w;
        }
        const unsigned int cw[8] = {c0b[buf].x, c0b[buf].y, c0b[buf].z, c0b[buf].w,
                                    c1b[buf].x, c1b[buf].y, c1b[buf].z, c1b[buf].w};
        const float mx = stb[buf].x, inv = stb[buf].y;

        // zero histogram (4 x b128 across the wave); prior row's gather reads precede
        // these writes in program order (within-wave LDS ordering) -> no barrier
        {
            uint4 z; z.x = 0; z.y = 0; z.z = 0; z.w = 0;
#pragma unroll
            for (int j = 0; j < 4; ++j) *reinterpret_cast<uint4*>(&sm[cb[j]]) = z;
        }

        float p[16];
#pragma unroll
        for (int e = 0; e < 16; ++e) p[e] = __expf(lg[e] - mx) * inv;

        // single atomic pass: histogram count + stable in-bucket offset
        unsigned int offv[16]; int swk[16];
#pragma unroll
        for (int e = 0; e < 16; ++e) {
            const unsigned int key = __float_as_uint(p[e]) >> 20;  // 11-bit monotone, <=1016
            swk[e] = SWZ((int)key);
            offv[e] = (base + e < CDIM) ? atomicAdd(&sm[swk[e]], 1u) : 0u;
        }

        // bucket suffix-scan: start[b] = sum_{b' > b} cnt[b']
        {
            unsigned int c16[16];
#pragma unroll
            for (int j = 0; j < 4; ++j) {
                const uint4 v4 = *reinterpret_cast<const uint4*>(&sm[cb[j]]);
                c16[4 * j] = v4.x; c16[4 * j + 1] = v4.y; c16[4 * j + 2] = v4.z; c16[4 * j + 3] = v4.w;
            }
            unsigned int lsum = 0;
#pragma unroll
            for (int e = 0; e < 16; ++e) lsum += c16[e];
            unsigned int suf = lsum;
#pragma unroll
            for (int off = 1; off < 64; off <<= 1) {
                const unsigned int u = __shfl_down(suf, off);
                if (lane + off < 64) suf += u;
            }
            unsigned int run = suf - lsum;
            unsigned int stv[16];
#pragma unroll
            for (int e = 15; e >= 0; --e) { stv[e] = run; run += c16[e]; }
#pragma unroll
            for (int j = 0; j < 4; ++j) {
                uint4 v4;
                v4.x = stv[4 * j]; v4.y = stv[4 * j + 1]; v4.z = stv[4 * j + 2]; v4.w = stv[4 * j + 3];
                *reinterpret_cast<uint4*>(&sm[cb[j]]) = v4;
            }
        }

        // rank = start[key] + offset
        int swr[16];
#pragma unroll
        for (int e = 0; e < 16; ++e) {
            const int rk = (base + e < CDIM) ? (int)(sm[swk[e]] + offv[e]) : 1023;
            swr[e] = SWZ(rk);
        }

        // scatter probs to rank order
#pragma unroll
        for (int e = 0; e < 16; ++e)
            if (base + e < CDIM) sm[swr[e]] = __float_as_uint(p[e]);

        // blocked read of sorted probs
        float sp[16];
#pragma unroll
        for (int j = 0; j < 4; ++j) {
            const uint4 v4 = *reinterpret_cast<const uint4*>(&sm[cb[j]]);
            sp[4 * j] = __uint_as_float(v4.x); sp[4 * j + 1] = __uint_as_float(v4.y);
            sp[4 * j + 2] = __uint_as_float(v4.z); sp[4 * j + 3] = __uint_as_float(v4.w);
        }
        const float spn_next = __shfl_down(sp[0], 1);
        float v[16];
#pragma unroll
        for (int e = 0; e < 16; ++e) {
            const int r = base + e;
            const float cv = bf2f((unsigned short)((cw[e >> 1] >> ((e & 1) * 16)) & 0xFFFFu));
            const float spn = (e < 15) ? sp[e + 1] : spn_next;
            float val;
            if (r < CDIM - 1) val = (sp[e] - spn) * cv;
            else if (r == CDIM - 1) val = cv;
            else val = 0.f;
            v[e] = val;
        }
        // suffix sum over rank space
        float lsuf[16], run = 0.f;
#pragma unroll
        for (int e = 15; e >= 0; --e) { run += v[e]; lsuf[e] = run; }
        float pi = run;
#pragma unroll
        for (int off = 1; off < 64; off <<= 1) {
            const float u = __shfl_up(pi, off);
            if (lane >= off) pi += u;
        }
        const float tot = __shfl(pi, 63);
        const float after = tot - pi;

        // S array overwrites sorted probs, gather by rank, add logits, store
#pragma unroll
        for (int j = 0; j < 4; ++j) {
            uint4 v4;
            v4.x = __float_as_uint(lsuf[4 * j] + after);
            v4.y = __float_as_uint(lsuf[4 * j + 1] + after);
            v4.z = __float_as_uint(lsuf[4 * j + 2] + after);
            v4.w = __float_as_uint(lsuf[4 * j + 3] + after);
            *reinterpret_cast<uint4*>(&sm[cb[j]]) = v4;
        }
        float f[16];
#pragma unroll
        for (int e = 0; e < 16; ++e) f[e] = __uint_as_float(sm[swr[e]]);
#pragma unroll
        for (int q = 0; q < 4; ++q) {
            const int c = base + (q << 2);
            if (c < CDIM) {
                float4 o;
                o.x = lg[q * 4] + f[q * 4];
                o.y = lg[q * 4 + 1] + f[q * 4 + 1];
                o.z = lg[q * 4 + 2] + f[q * 4 + 2];
                o.w = lg[q * 4 + 3] + f[q * 4 + 3];
                *reinterpret_cast<float4*>(out + (size_t)grow * CDIM + c) = o;
            }
        }
    }
}

// ---------------- host ----------------
extern "C" void kernel_launch(void* const* d_in, const int* in_sizes, int n_in,
                              void* d_out, int out_size, void* d_ws, size_t ws_size,
                              hipStream_t stream) {
    const float* logits = (const float*)d_in[0];
    const float* W1 = (const float*)d_in[1];
    const float* b1 = (const float*)d_in[2];
    const float* W2 = (const float*)d_in[3];
    const float* b2 = (const float*)d_in[4];
    const float* W3 = (const float*)d_in[5];
    const float* b3 = (const float*)d_in[6];
    float* out = (float*)d_out;

    char* ws = (char*)d_ws;
    unsigned short* prob = (unsigned short*)ws;                 // 64 MB (CPAD stride)
    unsigned short* h12  = (unsigned short*)(ws + 67108864);    // 8 MB: h1, then h2 in-place
    float2*         rstat= (float2*)(ws + 75497472);            // 256 KB
    unsigned short* W1t  = (unsigned short*)(ws + 75759616);    // 256 KB
    unsigned short* W2t  = (unsigned short*)(ws + 76021760);    // 32 KB
    unsigned short* W3t  = (unsigned short*)(ws + 76054528);    // 256 KB -> 76.3 MB total
    unsigned short* cal  = prob;  // prob dead after gemm1; cal compact ldo=CDIM

    k_prep<<<512, 256, 0, stream>>>(W1, W2, W3, W1t, W2t, W3t);
    k_softmax<<<BROWS / 4, 256, 0, stream>>>(logits, prob, rstat);
    k_gemm<0><<<dim3(BROWS / 128, 1), 512, 0, stream>>>(prob, CPAD, W1t, CPAD, b1, h12, HDIM, CPAD, 0);
    k_gemm<0><<<dim3(BROWS / 128, 1), 512, 0, stream>>>(h12, HDIM, W2t, HDIM, b2, h12, HDIM, HDIM, 0);
    k_gemm<1><<<dim3(BROWS / 128, 8), 512, 0, stream>>>(h12, HDIM, W3t, HDIM, b3, cal, CDIM, HDIM, CDIM);
    k_sortfinish<<<BROWS / 16, 256, 0, stream>>>(logits, rstat, cal, out);
}